// Round 15
// baseline (1113.999 us; speedup 1.0000x reference)
//
#include <hip/hip_runtime.h>
#include <hip/hip_bf16.h>
#include <math.h>

// Problem constants (B=8, N=1024, D=256, L=4, M=1024, H=8, dh=32, K=64 clusters)
#define BN 8192           // B*N rows
#define DMODEL 256
#define FFN 1024
#define NCLUST 64

typedef unsigned short u16;
typedef unsigned int u32;
typedef __attribute__((ext_vector_type(8))) short s16x8;      // 8 bf16 (4 VGPRs) MFMA frag
typedef __attribute__((ext_vector_type(8))) unsigned short u16x8;
typedef __attribute__((ext_vector_type(4))) unsigned short u16x4;
typedef __attribute__((ext_vector_type(4))) float f32x4;

__device__ __forceinline__ float bf2f(u16 v) {
    union { unsigned int u; float f; } w; w.u = ((unsigned int)v) << 16; return w.f;
}
__device__ __forceinline__ u16 f2bf(float f) {
    union { float f; unsigned int u; } w; w.f = f;
    unsigned int r = w.u + 0x7fffu + ((w.u >> 16) & 1u);
    return (u16)(r >> 16);
}
// packed RNE f32->bf16 pair: lo in [15:0], hi in [31:16]; bit-identical to f2bf for normals
__device__ __forceinline__ u32 cvtpk(float lo, float hi) {
    u32 r;
    asm("v_cvt_pk_bf16_f32 %0, %1, %2" : "=v"(r) : "v"(lo), "v"(hi));
    return r;
}
__device__ __forceinline__ float u2f(u32 u) { union { u32 u; float f; } w; w.u = u; return w.f; }

// async global->LDS, 16B per lane. LDS dest = wave-uniform base + lane*16 (linear);
// swizzled layouts are achieved by pre-swizzling the per-lane GLOBAL source column.
__device__ __forceinline__ void gl16(const u16* g, u16* l) {
    __builtin_amdgcn_global_load_lds((const __attribute__((address_space(1))) u32*)g,
                                     (__attribute__((address_space(3))) u32*)l, 16, 0, 0);
}

// barrier that does NOT drain vmcnt: LDS-visibility only. In-flight global/gl16 loads survive.
#define BARRIER_LGKM() asm volatile("s_waitcnt lgkmcnt(0)\n\ts_barrier" ::: "memory")
#define MEMFENCE_ORDER() asm volatile("" ::: "memory")

// XOR-swizzled LDS index helpers (u16 units).
__device__ __forceinline__ int sw32(int row, int col) { return row * 32 + (col ^ (((row >> 1) & 3) << 3)); }
__device__ __forceinline__ int sw64(int row, int col) { return row * 64 + (col ^ ((row & 7) << 3)); }
template<int BK>
__device__ __forceinline__ int swk(int row, int col) {
    if constexpr (BK == 32) return row * 32 + (col ^ (((row >> 1) & 3) << 3));
    else                    return row * 64 + (col ^ ((row & 7) << 3));
}

// ---------------- LayerNorm: one wave per row, float4 + shuffle reduce; emits bf16 h/l ----------------
__global__ __launch_bounds__(256) void ln_wave(const float* __restrict__ x, const float* __restrict__ g,
                                               const float* __restrict__ b, u16* __restrict__ yh,
                                               u16* __restrict__ yl) {
    int t = threadIdx.x, w = t >> 6, l = t & 63;
    int row = blockIdx.x * 4 + w;
    const float* xr = x + (size_t)row * DMODEL;
    float4 v = *reinterpret_cast<const float4*>(xr + l * 4);
    float s = v.x + v.y + v.z + v.w;
    for (int off = 1; off < 64; off <<= 1) s += __shfl_xor(s, off);
    float mean = s * (1.0f / 256.0f);
    float4 dv = make_float4(v.x - mean, v.y - mean, v.z - mean, v.w - mean);
    float vs = dv.x * dv.x + dv.y * dv.y + dv.z * dv.z + dv.w * dv.w;
    for (int off = 1; off < 64; off <<= 1) vs += __shfl_xor(vs, off);
    float rs = rsqrtf(vs * (1.0f / 256.0f) + 1e-5f);
    float4 gg = *reinterpret_cast<const float4*>(g + l * 4);
    float4 bb = *reinterpret_cast<const float4*>(b + l * 4);
    float os[4] = {dv.x * rs * gg.x + bb.x, dv.y * rs * gg.y + bb.y,
                   dv.z * rs * gg.z + bb.z, dv.w * rs * gg.w + bb.w};
    u16x4 hv, lv;
#pragma unroll
    for (int j = 0; j < 4; j++) { u16 hh = f2bf(os[j]); hv[j] = hh; lv[j] = f2bf(os[j] - bf2f(hh)); }
    size_t o = (size_t)row * DMODEL + l * 4;
    *reinterpret_cast<u16x4*>(yh + o) = hv;
    *reinterpret_cast<u16x4*>(yl + o) = lv;
}

// ---------------- Weight convert: one fused launch per layer (5 weights, 192 blocks) --------------
__device__ __forceinline__ void wconv_body(const float* __restrict__ W, u16* __restrict__ th,
                                           u16* __restrict__ tl, int K, int N, int bx, int by) {
    __shared__ float T[64][65];
    int k0 = by * 64, n0 = bx * 64;
    int t = threadIdx.x;
    int r = t >> 4, c4 = (t & 15) * 4;
#pragma unroll
    for (int i = 0; i < 4; i++) {
        float4 x = *reinterpret_cast<const float4*>(W + (size_t)(k0 + r + 16 * i) * N + n0 + c4);
        T[r + 16 * i][c4] = x.x; T[r + 16 * i][c4 + 1] = x.y;
        T[r + 16 * i][c4 + 2] = x.z; T[r + 16 * i][c4 + 3] = x.w;
    }
    __syncthreads();
#pragma unroll
    for (int i = 0; i < 4; i++) {
        int n = r + 16 * i;
        u16x4 h4, l4;
#pragma unroll
        for (int j = 0; j < 4; j++) {
            float v = T[c4 + j][n];
            u16 h = f2bf(v);
            h4[j] = h; l4[j] = f2bf(v - bf2f(h));
        }
        *reinterpret_cast<u16x4*>(th + (size_t)(n0 + n) * K + k0 + c4) = h4;
        *reinterpret_cast<u16x4*>(tl + (size_t)(n0 + n) * K + k0 + c4) = l4;
    }
}

__global__ __launch_bounds__(256) void wconv_all(const float* __restrict__ Wq, const float* __restrict__ Wkv,
                                                 const float* __restrict__ Wo, const float* __restrict__ W1,
                                                 const float* __restrict__ W2,
                                                 u16* __restrict__ wqkvh, u16* __restrict__ wqkvl,
                                                 u16* __restrict__ woh, u16* __restrict__ wol,
                                                 u16* __restrict__ w1h, u16* __restrict__ w1l,
                                                 u16* __restrict__ w2h, u16* __restrict__ w2l) {
    int f = blockIdx.x;
    if (f < 16)       wconv_body(Wq,  wqkvh,               wqkvl,               256, 256,  f & 3,  f >> 2);
    else if (f < 48)  { int g = f - 16;  wconv_body(Wkv, wqkvh + 65536,       wqkvl + 65536,       256, 512,  g & 7,  g >> 3); }
    else if (f < 64)  { int g = f - 48;  wconv_body(Wo,  woh,                 wol,                 256, 256,  g & 3,  g >> 2); }
    else if (f < 128) { int g = f - 64;  wconv_body(W1,  w1h,                 w1l,                 256, 1024, g & 15, g >> 4); }
    else              { int g = f - 128; wconv_body(W2,  w2h,                 w2l,                 1024, 256, g & 3,  g >> 2); }
}

// ---------------- MFMA GEMM (bf16x2): dbuf gl16 staging, counted-vmcnt no-drain schedule ----------
// XCD-aware bijective block swizzle (grids divisible by 8): each XCD gets a contiguous by-band,
// so A-panel re-reads hit its own L2. Pure block->tile permutation (bit-identical output).
template<int BM, int BNT, int BK>
__global__ __launch_bounds__(256) void gemm_t(const u16* __restrict__ Ath, const u16* __restrict__ Atl,
                                              const u16* __restrict__ Bth, const u16* __restrict__ Btl,
                                              const float* __restrict__ bias, const float* __restrict__ resid,
                                              float* __restrict__ Cf, u16* __restrict__ Ch, u16* __restrict__ Cl,
                                              int M, int N, int K, int fuse_gelu) {
    __shared__ u16 Ah[2][BM * BK], Al[2][BM * BK];
    __shared__ u16 Bh[2][BNT * BK], Bl[2][BNT * BK];
    constexpr int WAVES_N = (BM == 128 && BNT == 64) ? 1 : 2;
    constexpr int WAVES_M = 4 / WAVES_N;
    constexpr int MI = BM / (16 * WAVES_M);
    constexpr int NI = BNT / (16 * WAVES_N);
    constexpr int SEGS = (BM + BNT) * BK / 1024;   // 1KB segments per wave per K-step
    constexpr int ROWS_SEG = 512 / BK;             // rows per segment
    constexpr int ASEG = BM / ROWS_SEG;            // segments per A h (or l) region
    constexpr int BSEG = BNT / ROWS_SEG;
    int t = threadIdx.x;
    // XCD-aware swizzle of the flattened block id (nwg % 8 == 0 for all launches)
    int gx = gridDim.x;
    int nwg = gx * gridDim.y;
    int lin = blockIdx.y * gx + blockIdx.x;
    int swz = (lin & 7) * (nwg >> 3) + (lin >> 3);
    int bx = swz % gx, by = swz / gx;
    int m0 = by * BM, n0 = bx * BNT;
    int L = t & 63, w = t >> 6, fr = L & 15, quad = L >> 4;
    int wm = (WAVES_N == 1) ? w : (w & 1);
    int wn = (WAVES_N == 1) ? 0 : (w >> 1);

    // per-seg global source (pre-swizzled col) + buf0 LDS dest + buf1 element delta
    const u16* gsrc[SEGS];
    u16* ldst[SEGS];
    u32 dlt[SEGS];
    {
        int lr, lc;
        if constexpr (BK == 32) { lr = L >> 2; lc = (L & 3) * 8; }
        else                    { lr = L >> 3; lc = (L & 7) * 8; }
#pragma unroll
        for (int i = 0; i < SEGS; i++) {
            int s = w * SEGS + i;
            const u16* gb; u16* lb; int r; u32 d;
            if (s < ASEG)                 { gb = Ath + (size_t)m0 * K; lb = &Ah[0][0]; r = s * ROWS_SEG;                 d = BM * BK; }
            else if (s < 2 * ASEG)        { gb = Atl + (size_t)m0 * K; lb = &Al[0][0]; r = (s - ASEG) * ROWS_SEG;        d = BM * BK; }
            else if (s < 2 * ASEG + BSEG) { gb = Bth + (size_t)n0 * K; lb = &Bh[0][0]; r = (s - 2 * ASEG) * ROWS_SEG;    d = BNT * BK; }
            else                          { gb = Btl + (size_t)n0 * K; lb = &Bl[0][0]; r = (s - 2 * ASEG - BSEG) * ROWS_SEG; d = BNT * BK; }
            int row = r + lr;
            int scol;
            if constexpr (BK == 32) scol = lc ^ (((row >> 1) & 3) << 3);
            else                    scol = lc ^ ((row & 7) << 3);
            gsrc[i] = gb + (size_t)row * K + scol;
            ldst[i] = lb + r * BK;
            dlt[i] = d;
        }
    }

    f32x4 acc[MI][NI];
#pragma unroll
    for (int i = 0; i < MI; i++)
#pragma unroll
        for (int j = 0; j < NI; j++) acc[i][j] = (f32x4){0.0f, 0.0f, 0.0f, 0.0f};

    const int NT = K / BK;
    // prologue: stage tile 0 into buf0
#pragma unroll
    for (int i = 0; i < SEGS; i++) gl16(gsrc[i], ldst[i]);

    for (int tt = 0; tt < NT; tt++) {
        asm volatile("s_waitcnt lgkmcnt(0)" ::: "memory");
        __builtin_amdgcn_s_barrier();            // A: buf^1 readers (tt-1) all done
        if (tt + 1 < NT) {
            int k0n = (tt + 1) * BK;
            u32 sel = (u32)((tt + 1) & 1);
#pragma unroll
            for (int i = 0; i < SEGS; i++) gl16(gsrc[i] + k0n, ldst[i] + sel * dlt[i]);
            asm volatile("s_waitcnt vmcnt(%0)" :: "n"(SEGS) : "memory");   // own tile tt landed
        } else {
            asm volatile("s_waitcnt vmcnt(0)" ::: "memory");
        }
        __builtin_amdgcn_s_barrier();            // B: everyone's tile tt landed
        __builtin_amdgcn_sched_barrier(0);
        int cb = tt & 1;
        const u16* AhB = &Ah[cb][0]; const u16* AlB = &Al[cb][0];
        const u16* BhB = &Bh[cb][0]; const u16* BlB = &Bl[cb][0];
#pragma unroll
        for (int kk = 0; kk < BK / 32; kk++) {
            int kc = kk * 32 + quad * 8;
            s16x8 ah[MI], al[MI];
#pragma unroll
            for (int mi = 0; mi < MI; mi++) {
                int row = wm * (MI * 16) + mi * 16 + fr;
                ah[mi] = *reinterpret_cast<const s16x8*>(&AhB[swk<BK>(row, kc)]);
                al[mi] = *reinterpret_cast<const s16x8*>(&AlB[swk<BK>(row, kc)]);
            }
            __builtin_amdgcn_s_setprio(1);
#pragma unroll
            for (int ni = 0; ni < NI; ni++) {
                int rn = wn * (NI * 16) + ni * 16 + fr;
                s16x8 bhf = *reinterpret_cast<const s16x8*>(&BhB[swk<BK>(rn, kc)]);
                s16x8 blf = *reinterpret_cast<const s16x8*>(&BlB[swk<BK>(rn, kc)]);
#pragma unroll
                for (int mi = 0; mi < MI; mi++) {
                    acc[mi][ni] = __builtin_amdgcn_mfma_f32_16x16x32_bf16(ah[mi], bhf, acc[mi][ni], 0, 0, 0);
                    acc[mi][ni] = __builtin_amdgcn_mfma_f32_16x16x32_bf16(ah[mi], blf, acc[mi][ni], 0, 0, 0);
                    acc[mi][ni] = __builtin_amdgcn_mfma_f32_16x16x32_bf16(al[mi], bhf, acc[mi][ni], 0, 0, 0);
                }
            }
            __builtin_amdgcn_s_setprio(0);
        }
    }
#pragma unroll
    for (int mi = 0; mi < MI; mi++) {
#pragma unroll
        for (int ni = 0; ni < NI; ni++) {
#pragma unroll
            for (int r = 0; r < 4; r++) {
                int row = m0 + wm * (MI * 16) + mi * 16 + quad * 4 + r;
                int col = n0 + wn * (NI * 16) + ni * 16 + fr;
                float v = acc[mi][ni][r];
                if (bias) v += bias[col];
                if (fuse_gelu) v = 0.5f * v * (1.0f + erff(v * 0.70710678118654752f));
                if (resid) v += resid[(size_t)row * N + col];
                size_t o = (size_t)row * N + col;
                if (Cf) Cf[o] = v;
                if (Ch) { u16 hh = f2bf(v); Ch[o] = hh; Cl[o] = f2bf(v - bf2f(hh)); }
            }
        }
    }
}

// ---------------- Attention v16: QBLK=128, V-frags hoisted to regs, defer-rescale fast path ------
// V fragments read from LDS ONCE per kt (shared by both subtiles' PV; was 2x). Rescale skipped
// when alpha==1.0 exactly (mnew==m_i) -> bit-identical output to attn14.
__global__ __launch_bounds__(256) void attn16(const u16* __restrict__ qkvh, const u16* __restrict__ qkvl,
                                              u16* __restrict__ aoh, u16* __restrict__ aol) {
    int bh = blockIdx.x, b = bh >> 3, h = bh & 7;
    int qt = blockIdx.y;   // 0..7, 128 Q-rows each
    int t = threadIdx.x, L = t & 63, w = t >> 6;
    int fr = L & 15, quad = L >> 4;
    __shared__ u16 KH[2][64 * 32], KL[2][64 * 32];    // 16KB dbuf, sw32 layout
    __shared__ u16 VTH[32 * 64], VTL[32 * 64];        // 8KB  V^T[d][kc], sw64 layout
    __shared__ u16 PH[4][16 * 64], PL[4][16 * 64];    // 16KB per-wave P tile (reused by both subtiles)
    const float scale = 0.17677669529663687f;  // 1/sqrt(32)
    const int ROWS = 768;

    // K staging via gl16: 8 segs (KH 4, KL 4), 2 per wave, precomputed addresses
    const u16* ksrc[2];
    u16* kdst[2];
    {
        int lr = L >> 2, lc = (L & 3) * 8;
#pragma unroll
        for (int i = 0; i < 2; i++) {
            int s = w * 2 + i;
            const u16* gb = (s < 4) ? qkvh : qkvl;
            u16* lb = (s < 4) ? &KH[0][0] : &KL[0][0];
            int r = (s & 3) * 16;
            int row = r + lr;
            int scol = lc ^ (((row >> 1) & 3) << 3);
            ksrc[i] = gb + ((size_t)(b * 1024) + row) * ROWS + 256 + h * 32 + scol;
            kdst[i] = lb + r * 32;
        }
    }

    // Q fragments for both subtiles: rows qt*128 + w*16 + fr and +64
    size_t qoff0 = (size_t)(b * 1024 + qt * 128 + w * 16 + fr) * ROWS + h * 32 + quad * 8;
    s16x8 aqh0 = *reinterpret_cast<const s16x8*>(qkvh + qoff0);
    s16x8 aql0 = *reinterpret_cast<const s16x8*>(qkvl + qoff0);
    s16x8 aqh1 = *reinterpret_cast<const s16x8*>(qkvh + qoff0 + (size_t)64 * ROWS);
    s16x8 aql1 = *reinterpret_cast<const s16x8*>(qkvl + qoff0 + (size_t)64 * ROWS);

    // V loads: thread -> kc pair 2vp,2vp+1, dims vd0..+3
    int vp = t >> 3, vd0 = (t & 7) * 4;
    const u16* vh_ptr = qkvh + (size_t)(b * 1024 + 2 * vp) * ROWS + 512 + h * 32 + vd0;
    const u16* vl_ptr = qkvl + (size_t)(b * 1024 + 2 * vp) * ROWS + 512 + h * 32 + vd0;
    u16x4 vh0, vh1, vl0, vl1;
#define LOADV(kt_) do { size_t o_ = (size_t)((kt_) * 64) * ROWS;                                  \
        vh0 = *reinterpret_cast<const u16x4*>(vh_ptr + o_);                                       \
        vh1 = *reinterpret_cast<const u16x4*>(vh_ptr + o_ + ROWS);                                \
        vl0 = *reinterpret_cast<const u16x4*>(vl_ptr + o_);                                       \
        vl1 = *reinterpret_cast<const u16x4*>(vl_ptr + o_ + ROWS); } while (0)

    gl16(ksrc[0], kdst[0]);    // K(0) -> buf0 (must precede V(0) loads: FIFO drain invariant)
    gl16(ksrc[1], kdst[1]);
    MEMFENCE_ORDER();
    LOADV(0);

    float m_0 = -1e30f, l_0 = 0.0f, m_1 = -1e30f, l_1 = 0.0f;
    f32x4 accA0, accA1, accB0, accB1;   // subtile0: accA*, subtile1: accB* (ns 0/1)
    accA0 = (f32x4){0.0f, 0.0f, 0.0f, 0.0f}; accA1 = accA0; accB0 = accA0; accB1 = accA0;

// softmax + P-write + conditional rescale + PV for one subtile. V-frags Vh/Vl come from
// enclosing-scope registers (loaded once per kt). Bit-identical to attn14's math: the
// rescale branch is skipped only when alpha == 1.0 exactly (mnew == M_I), and x*1.0 is exact.
#define SM_PV(SV, M_I, L_I, ACC0, ACC1) do {                                                      \
        float p[16];                                                                              \
        float ml = -1e30f;                                                                        \
        _Pragma("unroll")                                                                         \
        for (int ni = 0; ni < 4; ni++)                                                            \
            _Pragma("unroll")                                                                     \
            for (int r = 0; r < 4; r++) { float v = SV[ni][r] * scale; p[ni * 4 + r] = v; ml = fmaxf(ml, v); } \
        ml = fmaxf(ml, __shfl_xor(ml, 16));                                                       \
        ml = fmaxf(ml, __shfl_xor(ml, 32));                                                       \
        float mnew = fmaxf(M_I, ml);                                                              \
        float rs = 0.0f;                                                                          \
        _Pragma("unroll")                                                                         \
        for (int i = 0; i < 16; i++) { float e = __expf(p[i] - mnew); p[i] = e; rs += e; }        \
        rs += __shfl_xor(rs, 16);                                                                 \
        rs += __shfl_xor(rs, 32);                                                                 \
        if (__all(ml <= M_I)) {                                                                   \
            L_I = L_I + rs;               /* alpha == 1.0 exactly: identity rescale skipped */    \
        } else {                                                                                  \
            float alpha = __expf(M_I - mnew);                                                     \
            M_I = mnew;                                                                           \
            L_I = L_I * alpha + rs;                                                               \
            float a4[4];                                                                          \
            _Pragma("unroll")                                                                     \
            for (int r = 0; r < 4; r++) a4[r] = __shfl(alpha, quad * 4 + r);                      \
            ACC0[0] *= a4[0]; ACC0[1] *= a4[1]; ACC0[2] *= a4[2]; ACC0[3] *= a4[3];               \
            ACC1[0] *= a4[0]; ACC1[1] *= a4[1]; ACC1[2] *= a4[2]; ACC1[3] *= a4[3];               \
        }                                                                                         \
        _Pragma("unroll")                                                                         \
        for (int ni = 0; ni < 4; ni++) {                                                          \
            float p0 = p[ni * 4], p1 = p[ni * 4 + 1], p2 = p[ni * 4 + 2], p3 = p[ni * 4 + 3];     \
            u32 qh01 = cvtpk(p0, p1), qh23 = cvtpk(p2, p3);                                       \
            float e0 = p0 - u2f(qh01 << 16);                                                      \
            float e1 = p1 - u2f(qh01 & 0xffff0000u);                                              \
            float e2 = p2 - u2f(qh23 << 16);                                                      \
            float e3 = p3 - u2f(qh23 & 0xffff0000u);                                              \
            u32 ql01 = cvtpk(e0, e1), ql23 = cvtpk(e2, e3);                                       \
            int c0 = sw64(fr, ni * 16 + quad * 4);                                                \
            int c1 = sw64(fr, ni * 16 + quad * 4 + 2);                                            \
            *reinterpret_cast<u32*>(&PH[w][c0]) = qh01;                                           \
            *reinterpret_cast<u32*>(&PH[w][c1]) = qh23;                                           \
            *reinterpret_cast<u32*>(&PL[w][c0]) = ql01;                                           \
            *reinterpret_cast<u32*>(&PL[w][c1]) = ql23;                                           \
        }                                                                                         \
        __builtin_amdgcn_s_setprio(1);                                                            \
        _Pragma("unroll")                                                                         \
        for (int ks = 0; ks < 2; ks++) {                                                          \
            s16x8 aph = *reinterpret_cast<s16x8*>(&PH[w][sw64(fr, ks * 32 + quad * 8)]);          \
            s16x8 apl = *reinterpret_cast<s16x8*>(&PL[w][sw64(fr, ks * 32 + quad * 8)]);          \
            ACC0 = __builtin_amdgcn_mfma_f32_16x16x32_bf16(aph, Vh[ks][0], ACC0, 0, 0, 0);        \
            ACC0 = __builtin_amdgcn_mfma_f32_16x16x32_bf16(aph, Vl[ks][0], ACC0, 0, 0, 0);        \
            ACC0 = __builtin_amdgcn_mfma_f32_16x16x32_bf16(apl, Vh[ks][0], ACC0, 0, 0, 0);        \
            ACC1 = __builtin_amdgcn_mfma_f32_16x16x32_bf16(aph, Vh[ks][1], ACC1, 0, 0, 0);        \
            ACC1 = __builtin_amdgcn_mfma_f32_16x16x32_bf16(aph, Vl[ks][1], ACC1, 0, 0, 0);        \
            ACC1 = __builtin_amdgcn_mfma_f32_16x16x32_bf16(apl, Vh[ks][1], ACC1, 0, 0, 0);        \
        }                                                                                         \
        __builtin_amdgcn_s_setprio(0);                                                            \
    } while (0)

#pragma unroll 2
    for (int kt = 0; kt < 16; kt++) {
        int cur = kt & 1;
        BARRIER_LGKM();                // A: K buf^1 + VT readers (kt-1) all done
        if (kt < 15) {                 // prefetch K(kt+1) -> buf^1 (survives both barriers)
            size_t koff = (size_t)((kt + 1) * 64) * ROWS;
            u32 sel = (u32)((kt + 1) & 1) * (64 * 32);
            gl16(ksrc[0] + koff, kdst[0] + sel);
            gl16(ksrc[1] + koff, kdst[1] + sel);
        }
        {   // VT write from prefetched V regs; the implicit V-wait also drains K(kt) (landed long ago)
#pragma unroll
            for (int i = 0; i < 4; i++) {
                int idx = sw64(vd0 + i, 2 * vp);
                *reinterpret_cast<u32*>(&VTH[idx]) = (u32)vh0[i] | ((u32)vh1[i] << 16);
                *reinterpret_cast<u32*>(&VTL[idx]) = (u32)vl0[i] | ((u32)vl1[i] << 16);
            }
        }
        BARRIER_LGKM();                // B: K(kt) + VT(kt) ready for all waves
        // S^T = K Q^T for both subtiles: K frags loaded once, 3 MFMA each
        f32x4 sv0[4], sv1[4];
        __builtin_amdgcn_s_setprio(1);
#pragma unroll
        for (int ni = 0; ni < 4; ni++) {
            s16x8 bkh = *reinterpret_cast<s16x8*>(&KH[cur][sw32(ni * 16 + fr, quad * 8)]);
            s16x8 bkl = *reinterpret_cast<s16x8*>(&KL[cur][sw32(ni * 16 + fr, quad * 8)]);
            f32x4 c0 = (f32x4){0.0f, 0.0f, 0.0f, 0.0f};
            c0 = __builtin_amdgcn_mfma_f32_16x16x32_bf16(bkh, aqh0, c0, 0, 0, 0);
            c0 = __builtin_amdgcn_mfma_f32_16x16x32_bf16(bkl, aqh0, c0, 0, 0, 0);
            c0 = __builtin_amdgcn_mfma_f32_16x16x32_bf16(bkh, aql0, c0, 0, 0, 0);
            sv0[ni] = c0;
            f32x4 c1 = (f32x4){0.0f, 0.0f, 0.0f, 0.0f};
            c1 = __builtin_amdgcn_mfma_f32_16x16x32_bf16(bkh, aqh1, c1, 0, 0, 0);
            c1 = __builtin_amdgcn_mfma_f32_16x16x32_bf16(bkl, aqh1, c1, 0, 0, 0);
            c1 = __builtin_amdgcn_mfma_f32_16x16x32_bf16(bkh, aql1, c1, 0, 0, 0);
            sv1[ni] = c1;
        }
        __builtin_amdgcn_s_setprio(0);
        // hoist V fragments to registers ONCE (shared by both subtiles' PV; overlaps softmax VALU)
        s16x8 Vh[2][2], Vl[2][2];   // [ks][ns]
#pragma unroll
        for (int ks = 0; ks < 2; ks++)
#pragma unroll
            for (int ns = 0; ns < 2; ns++) {
                Vh[ks][ns] = *reinterpret_cast<s16x8*>(&VTH[sw64(ns * 16 + fr, ks * 32 + quad * 8)]);
                Vl[ks][ns] = *reinterpret_cast<s16x8*>(&VTL[sw64(ns * 16 + fr, ks * 32 + quad * 8)]);
            }
        if (kt < 15) LOADV(kt + 1);    // V(kt+1) regs; consumed at next iter's VT write
        SM_PV(sv0, m_0, l_0, accA0, accA1);   // subtile 0 (P tile reused; same-wave ordering)
        SM_PV(sv1, m_1, l_1, accB0, accB1);   // subtile 1
    }
#undef SM_PV
#undef LOADV
    // write O as bf16 h/l: subtile 0 rows qt*128+w*16+quad*4+r, subtile 1 rows +64
    float invl0 = 1.0f / l_0, invl1 = 1.0f / l_1;
#pragma unroll
    for (int r = 0; r < 4; r++) {
        float iv0 = __shfl(invl0, quad * 4 + r);
        float iv1 = __shfl(invl1, quad * 4 + r);
        size_t rb0 = ((size_t)(b * 1024 + qt * 128 + w * 16 + quad * 4 + r)) * DMODEL + h * 32;
        size_t rb1 = rb0 + (size_t)64 * DMODEL;
        float v0 = accA0[r] * iv0, v1 = accA1[r] * iv0;
        u16 h0 = f2bf(v0); aoh[rb0 + fr] = h0;      aol[rb0 + fr] = f2bf(v0 - bf2f(h0));
        u16 h1 = f2bf(v1); aoh[rb0 + 16 + fr] = h1; aol[rb0 + 16 + fr] = f2bf(v1 - bf2f(h1));
        float v2 = accB0[r] * iv1, v3 = accB1[r] * iv1;
        u16 h2 = f2bf(v2); aoh[rb1 + fr] = h2;      aol[rb1 + fr] = f2bf(v2 - bf2f(h2));
        u16 h3 = f2bf(v3); aoh[rb1 + 16 + fr] = h3; aol[rb1 + 16 + fr] = f2bf(v3 - bf2f(h3));
    }
}

// ---------------- K-means: fused dist+argmin, stage-once centers, 2 rows/thread ------------------
__global__ __launch_bounds__(64) void csq_k(const float* __restrict__ centers, float* __restrict__ csq) {
    int j = blockIdx.x, l = threadIdx.x;
    float4 c4 = *reinterpret_cast<const float4*>(centers + j * DMODEL + l * 4);
    float s = c4.x * c4.x + c4.y * c4.y + c4.z * c4.z + c4.w * c4.w;
    for (int off = 1; off < 64; off <<= 1) s += __shfl_xor(s, off);
    if (l == 0) csq[j] = s;
}

// 32 rows x 64 clusters per block, 2 rows/thread; grid 256 (1 block/CU). Each staged-center b128
// read feeds BOTH rows -> LDS issue per row halved. k-ascending fp32 dot order per (row,cluster)
// identical to prior versions -> bit-identical labels.
__global__ __launch_bounds__(256) void km_distmin(const float* __restrict__ A, const float* __restrict__ Cn,
                                                  const float* __restrict__ csq, int* __restrict__ labels) {
    __shared__ float Cs[256][68];
    int t = threadIdx.x, tx = t & 15, ty = t >> 4;
    int m0 = blockIdx.x * 32;
    {   // stage centers transposed: thread -> col j = t&63, k-chunk (t>>6)*64
        int j = t & 63, kc = (t >> 6) * 64;
#pragma unroll
        for (int i = 0; i < 16; i++) {
            float4 c4 = *reinterpret_cast<const float4*>(Cn + (size_t)j * DMODEL + kc + i * 4);
            Cs[kc + i * 4 + 0][j] = c4.x; Cs[kc + i * 4 + 1][j] = c4.y;
            Cs[kc + i * 4 + 2][j] = c4.z; Cs[kc + i * 4 + 3][j] = c4.w;
        }
    }
    __syncthreads();
    const float* ar0 = A + (size_t)(m0 + ty) * DMODEL;
    const float* ar1 = A + (size_t)(m0 + 16 + ty) * DMODEL;
    float acc0[4] = {}, acc1[4] = {};
    for (int kb = 0; kb < 64; kb++) {
        float4 a0 = *reinterpret_cast<const float4*>(ar0 + kb * 4);
        float4 a1 = *reinterpret_cast<const float4*>(ar1 + kb * 4);
        float4 b0 = *reinterpret_cast<float4*>(&Cs[kb * 4 + 0][tx * 4]);
        float4 b1 = *reinterpret_cast<float4*>(&Cs[kb * 4 + 1][tx * 4]);
        float4 b2 = *reinterpret_cast<float4*>(&Cs[kb * 4 + 2][tx * 4]);
        float4 b3 = *reinterpret_cast<float4*>(&Cs[kb * 4 + 3][tx * 4]);
        acc0[0] += a0.x * b0.x; acc0[1] += a0.x * b0.y; acc0[2] += a0.x * b0.z; acc0[3] += a0.x * b0.w;
        acc0[0] += a0.y * b1.x; acc0[1] += a0.y * b1.y; acc0[2] += a0.y * b1.z; acc0[3] += a0.y * b1.w;
        acc0[0] += a0.z * b2.x; acc0[1] += a0.z * b2.y; acc0[2] += a0.z * b2.z; acc0[3] += a0.z * b2.w;
        acc0[0] += a0.w * b3.x; acc0[1] += a0.w * b3.y; acc0[2] += a0.w * b3.z; acc0[3] += a0.w * b3.w;
        acc1[0] += a1.x * b0.x; acc1[1] += a1.x * b0.y; acc1[2] += a1.x * b0.z; acc1[3] += a1.x * b0.w;
        acc1[0] += a1.y * b1.x; acc1[1] += a1.y * b1.y; acc1[2] += a1.y * b1.z; acc1[3] += a1.y * b1.w;
        acc1[0] += a1.z * b2.x; acc1[1] += a1.z * b2.y; acc1[2] += a1.z * b2.z; acc1[3] += a1.z * b2.w;
        acc1[0] += a1.w * b3.x; acc1[1] += a1.w * b3.y; acc1[2] += a1.w * b3.z; acc1[3] += a1.w * b3.w;
    }
    float4 cs4 = *reinterpret_cast<const float4*>(csq + tx * 4);
    float csv[4] = {cs4.x, cs4.y, cs4.z, cs4.w};
    {
        float best = csv[0] - 2.0f * acc0[0]; int bi = tx * 4;
#pragma unroll
        for (int j = 1; j < 4; j++) {
            float v = csv[j] - 2.0f * acc0[j];
            if (v < best) { best = v; bi = tx * 4 + j; }
        }
        for (int off = 1; off < 16; off <<= 1) {
            float ov = __shfl_xor(best, off);
            int oi = __shfl_xor(bi, off);
            if (ov < best || (ov == best && oi < bi)) { best = ov; bi = oi; }
        }
        if (tx == 0) labels[m0 + ty] = bi;
    }
    {
        float best = csv[0] - 2.0f * acc1[0]; int bi = tx * 4;
#pragma unroll
        for (int j = 1; j < 4; j++) {
            float v = csv[j] - 2.0f * acc1[j];
            if (v < best) { best = v; bi = tx * 4 + j; }
        }
        for (int off = 1; off < 16; off <<= 1) {
            float ov = __shfl_xor(best, off);
            int oi = __shfl_xor(bi, off);
            if (ov < best || (ov == best && oi < bi)) { best = ov; bi = oi; }
        }
        if (tx == 0) labels[m0 + 16 + ty] = bi;
    }
}

// block (c, j): scan chunk c's 256 labels, accumulate rows with lab==j. Uniform branch, no atomics.
__global__ __launch_bounds__(256) void km_segsum(const int* __restrict__ labels, const float* __restrict__ xf,
                                                 float* __restrict__ sums32, float* __restrict__ counts32) {
    int c = blockIdx.x, j = blockIdx.y, t = threadIdx.x;
    __shared__ int labs[256];
    if (t < 64) {
        int4 l4 = *reinterpret_cast<const int4*>(labels + c * 256 + t * 4);
        labs[t * 4] = l4.x; labs[t * 4 + 1] = l4.y; labs[t * 4 + 2] = l4.z; labs[t * 4 + 3] = l4.w;
    }
    __syncthreads();
    float acc = 0.0f, cnt = 0.0f;
    const float* xb = xf + (size_t)c * 256 * DMODEL;
    for (int i = 0; i < 256; i++) {
        if (labs[i] == j) { acc += xb[(size_t)i * DMODEL + t]; cnt += 1.0f; }
    }
    sums32[((size_t)c * NCLUST + j) * DMODEL + t] = acc;
    if (t == 0) counts32[c * NCLUST + j] = cnt;
}

__global__ __launch_bounds__(256) void km_update(float* __restrict__ centers, const float* __restrict__ sums32,
                                                 const float* __restrict__ counts32, float* __restrict__ csq) {
    __shared__ float red[256];
    int j = blockIdx.x, d = threadIdx.x;
    float c = 0.0f;
#pragma unroll
    for (int cc = 0; cc < 32; cc++) c += counts32[cc * NCLUST + j];
    float sv = 0.0f;
#pragma unroll
    for (int cc = 0; cc < 32; cc++) sv += sums32[((size_t)cc * NCLUST + j) * DMODEL + d];
    float cv = centers[j * DMODEL + d];
    if (c > 0.0f) cv = sv / fmaxf(c, 1.0f);
    centers[j * DMODEL + d] = cv;
    red[d] = cv * cv;
    __syncthreads();
    for (int off = 128; off; off >>= 1) { if (d < off) red[d] += red[d + off]; __syncthreads(); }
    if (d == 0) csq[j] = red[0];
}

__global__ __launch_bounds__(256) void nproj(const float* __restrict__ centers, const float* __restrict__ kW,
                                             const float* __restrict__ kb2, float* __restrict__ outc) {
    int idx = blockIdx.x * 256 + threadIdx.x;
    if (idx >= NCLUST * DMODEL) return;
    int row = idx >> 8, col = idx & 255;
    const float* cr = centers + row * DMODEL;
    float acc = 0.0f;
    for (int d = 0; d < DMODEL; d++) acc += cr[d] * kW[(size_t)d * DMODEL + col];
    outc[idx] = acc + kb2[col];
}

__global__ __launch_bounds__(256) void km_gather(const int* __restrict__ labels, const float* __restrict__ outc,
                                                 float* __restrict__ out) {
    int t = threadIdx.x;
#pragma unroll
    for (int r = 0; r < 4; r++) {
        int i = blockIdx.x * 4 + r;
        int lab = labels[i];
        out[(size_t)i * DMODEL + t] = outc[lab * DMODEL + t];
    }
}

extern "C" void kernel_launch(void* const* d_in, const int* in_sizes, int n_in,
                              void* d_out, int out_size, void* d_ws, size_t ws_size,
                              hipStream_t stream) {
    const float* x_in  = (const float*)d_in[0];
    const float* ln1_g = (const float*)d_in[1];
    const float* ln1_b = (const float*)d_in[2];
    const float* Wq    = (const float*)d_in[3];
    const float* Wkv   = (const float*)d_in[4];
    const float* Wo    = (const float*)d_in[5];
    const float* bo    = (const float*)d_in[6];
    const float* ln2_g = (const float*)d_in[7];
    const float* ln2_b = (const float*)d_in[8];
    const float* W1    = (const float*)d_in[9];
    const float* b1    = (const float*)d_in[10];
    const float* W2    = (const float*)d_in[11];
    const float* b2    = (const float*)d_in[12];
    const float* kWp   = (const float*)d_in[13];
    const float* kbp   = (const float*)d_in[14];
    float* out = (float*)d_out;

    const size_t NEEDED = 53477376;
    if (ws_size < NEEDED) {
        hipMemsetAsync(d_out, 0, (size_t)out_size * sizeof(float), stream);
        return;   // signature: absmax ~0.707 => workspace too small
    }

    char* ws = (char*)d_ws;
    float* xf      = (float*)(ws);                 // 8 MB fp32 residual stream
    u16*   xnh     = (u16*)  (ws + 8388608);       // 4 MB  ln out h
    u16*   xnl     = (u16*)  (ws + 12582912);      // 4 MB  ln out l
    u16*   aoh     = xnh;                          // attn out aliases xn (xn dead after QKV gemm)
    u16*   aol     = xnl;
    u16*   qkvh    = (u16*)  (ws + 16777216);      // 12 MB (8192x768 u16) -> ends 29360128
    u16*   qkvl    = (u16*)  (ws + 29360128);      // 12 MB -> ends 41943040
    u16*   hbh     = (u16*)  (ws + 16777216);      // 16 MB (qkv dead during FFN)
    u16*   hbl     = (u16*)  (ws + 33554432);      // 16 MB -> ends 50331648
    float* centers = (float*)(ws + 41943040);      // 64 KB -> 42008576
    float* csqb    = (float*)(ws + 42008576);      // 256 B -> 42008832
    float* counts32= (float*)(ws + 42008832);      // 8 KB  -> 42017024
    int*   labels  = (int*)  (ws + 42017024);      // 32 KB -> 42049792
    float* outc    = (float*)(ws + 42049792);      // 64 KB -> 42115328
    float* sums32  = (float*)(ws + 42115328);      // 2 MB  -> 44212480
    u16*   wr      = (u16*)  (ws + 50331648);
    u16 *wqkvh = wr,          *wqkvl = wr + 196608;   // 768x256 each
    u16 *woh = wr + 393216,   *wol = wr + 458752;
    u16 *w1h = wr + 524288,   *w1l = wr + 786432;
    u16 *w2h = wr + 1048576,  *w2l = wr + 1310720;

    hipMemcpyAsync(xf, x_in, (size_t)BN * DMODEL * sizeof(float), hipMemcpyDeviceToDevice, stream);

    for (int l = 0; l < 4; l++) {
        wconv_all<<<192, 256, 0, stream>>>(Wq + (size_t)l * 65536, Wkv + (size_t)l * 131072,
                                           Wo + (size_t)l * 65536, W1 + (size_t)l * 262144,
                                           W2 + (size_t)l * 262144,
                                           wqkvh, wqkvl, woh, wol, w1h, w1l, w2h, w2l);

        ln_wave<<<BN / 4, 256, 0, stream>>>(xf, ln1_g + l * 256, ln1_b + l * 256, xnh, xnl);
        gemm_t<128, 128, 32><<<dim3(6, 64), 256, 0, stream>>>(xnh, xnl, wqkvh, wqkvl, nullptr, nullptr,
                                                              nullptr, qkvh, qkvl, BN, 768, 256, 0);
        attn16<<<dim3(64, 8), 256, 0, stream>>>(qkvh, qkvl, aoh, aol);
        gemm_t<64, 64, 64><<<dim3(4, 128), 256, 0, stream>>>(aoh, aol, woh, wol, bo + l * 256, xf,
                                                             xf, nullptr, nullptr, BN, 256, 256, 0);
        ln_wave<<<BN / 4, 256, 0, stream>>>(xf, ln2_g + l * 256, ln2_b + l * 256, xnh, xnl);
        gemm_t<128, 128, 32><<<dim3(8, 64), 256, 0, stream>>>(xnh, xnl, w1h, w1l, b1 + l * 1024, nullptr,
                                                              nullptr, hbh, hbl, BN, 1024, 256, 1);
        gemm_t<64, 64, 64><<<dim3(4, 128), 256, 0, stream>>>(hbh, hbl, w2h, w2l, b2 + l * 256, xf,
                                                             xf, nullptr, nullptr, BN, 256, 1024, 0);
    }

    hipMemcpyAsync(centers, xf, NCLUST * DMODEL * sizeof(float), hipMemcpyDeviceToDevice, stream);
    csq_k<<<64, 64, 0, stream>>>(centers, csqb);
    for (int it = 0; it < 10; it++) {
        km_distmin<<<256, 256, 0, stream>>>(xf, centers, csqb, labels);
        km_segsum<<<dim3(32, NCLUST), 256, 0, stream>>>(labels, xf, sums32, counts32);
        km_update<<<64, 256, 0, stream>>>(centers, sums32, counts32, csqb);
    }
    km_distmin<<<256, 256, 0, stream>>>(xf, centers, csqb, labels);
    nproj<<<64, 256, 0, stream>>>(centers, kWp, kbp, outc);
    km_gather<<<BN / 4, 256, 0, stream>>>(labels, outc, out);
}

// Round 16
// 1073.282 us; speedup vs baseline: 1.0379x; 1.0379x over previous
//
#include <hip/hip_runtime.h>
#include <hip/hip_bf16.h>
#include <math.h>

// Problem constants (B=8, N=1024, D=256, L=4, M=1024, H=8, dh=32, K=64 clusters)
#define BN 8192           // B*N rows
#define DMODEL 256
#define FFN 1024
#define NCLUST 64

typedef unsigned short u16;
typedef unsigned int u32;
typedef __attribute__((ext_vector_type(8))) short s16x8;      // 8 bf16 (4 VGPRs) MFMA frag
typedef __attribute__((ext_vector_type(8))) unsigned short u16x8;
typedef __attribute__((ext_vector_type(4))) unsigned short u16x4;
typedef __attribute__((ext_vector_type(4))) float f32x4;

__device__ __forceinline__ float bf2f(u16 v) {
    union { unsigned int u; float f; } w; w.u = ((unsigned int)v) << 16; return w.f;
}
__device__ __forceinline__ u16 f2bf(float f) {
    union { float f; unsigned int u; } w; w.f = f;
    unsigned int r = w.u + 0x7fffu + ((w.u >> 16) & 1u);
    return (u16)(r >> 16);
}
// packed RNE f32->bf16 pair: lo in [15:0], hi in [31:16]; bit-identical to f2bf for normals
__device__ __forceinline__ u32 cvtpk(float lo, float hi) {
    u32 r;
    asm("v_cvt_pk_bf16_f32 %0, %1, %2" : "=v"(r) : "v"(lo), "v"(hi));
    return r;
}
__device__ __forceinline__ float u2f(u32 u) { union { u32 u; float f; } w; w.u = u; return w.f; }

// async global->LDS, 16B per lane. LDS dest = wave-uniform base + lane*16 (linear);
// swizzled layouts are achieved by pre-swizzling the per-lane GLOBAL source column.
__device__ __forceinline__ void gl16(const u16* g, u16* l) {
    __builtin_amdgcn_global_load_lds((const __attribute__((address_space(1))) u32*)g,
                                     (__attribute__((address_space(3))) u32*)l, 16, 0, 0);
}

// barrier that does NOT drain vmcnt: LDS-visibility only. In-flight global/gl16 loads survive.
#define BARRIER_LGKM() asm volatile("s_waitcnt lgkmcnt(0)\n\ts_barrier" ::: "memory")
#define MEMFENCE_ORDER() asm volatile("" ::: "memory")

// XOR-swizzled LDS index helpers (u16 units).
__device__ __forceinline__ int sw32(int row, int col) { return row * 32 + (col ^ (((row >> 1) & 3) << 3)); }
__device__ __forceinline__ int sw64(int row, int col) { return row * 64 + (col ^ ((row & 7) << 3)); }
template<int BK>
__device__ __forceinline__ int swk(int row, int col) {
    if constexpr (BK == 32) return row * 32 + (col ^ (((row >> 1) & 3) << 3));
    else                    return row * 64 + (col ^ ((row & 7) << 3));
}

// ---------------- LayerNorm: one wave per row, float4 + shuffle reduce; emits bf16 h/l ----------------
__global__ __launch_bounds__(256) void ln_wave(const float* __restrict__ x, const float* __restrict__ g,
                                               const float* __restrict__ b, u16* __restrict__ yh,
                                               u16* __restrict__ yl) {
    int t = threadIdx.x, w = t >> 6, l = t & 63;
    int row = blockIdx.x * 4 + w;
    const float* xr = x + (size_t)row * DMODEL;
    float4 v = *reinterpret_cast<const float4*>(xr + l * 4);
    float s = v.x + v.y + v.z + v.w;
    for (int off = 1; off < 64; off <<= 1) s += __shfl_xor(s, off);
    float mean = s * (1.0f / 256.0f);
    float4 dv = make_float4(v.x - mean, v.y - mean, v.z - mean, v.w - mean);
    float vs = dv.x * dv.x + dv.y * dv.y + dv.z * dv.z + dv.w * dv.w;
    for (int off = 1; off < 64; off <<= 1) vs += __shfl_xor(vs, off);
    float rs = rsqrtf(vs * (1.0f / 256.0f) + 1e-5f);
    float4 gg = *reinterpret_cast<const float4*>(g + l * 4);
    float4 bb = *reinterpret_cast<const float4*>(b + l * 4);
    float os[4] = {dv.x * rs * gg.x + bb.x, dv.y * rs * gg.y + bb.y,
                   dv.z * rs * gg.z + bb.z, dv.w * rs * gg.w + bb.w};
    u16x4 hv, lv;
#pragma unroll
    for (int j = 0; j < 4; j++) { u16 hh = f2bf(os[j]); hv[j] = hh; lv[j] = f2bf(os[j] - bf2f(hh)); }
    size_t o = (size_t)row * DMODEL + l * 4;
    *reinterpret_cast<u16x4*>(yh + o) = hv;
    *reinterpret_cast<u16x4*>(yl + o) = lv;
}

// ---------------- Weight convert: one fused launch per layer (5 weights, 192 blocks) --------------
__device__ __forceinline__ void wconv_body(const float* __restrict__ W, u16* __restrict__ th,
                                           u16* __restrict__ tl, int K, int N, int bx, int by) {
    __shared__ float T[64][65];
    int k0 = by * 64, n0 = bx * 64;
    int t = threadIdx.x;
    int r = t >> 4, c4 = (t & 15) * 4;
#pragma unroll
    for (int i = 0; i < 4; i++) {
        float4 x = *reinterpret_cast<const float4*>(W + (size_t)(k0 + r + 16 * i) * N + n0 + c4);
        T[r + 16 * i][c4] = x.x; T[r + 16 * i][c4 + 1] = x.y;
        T[r + 16 * i][c4 + 2] = x.z; T[r + 16 * i][c4 + 3] = x.w;
    }
    __syncthreads();
#pragma unroll
    for (int i = 0; i < 4; i++) {
        int n = r + 16 * i;
        u16x4 h4, l4;
#pragma unroll
        for (int j = 0; j < 4; j++) {
            float v = T[c4 + j][n];
            u16 h = f2bf(v);
            h4[j] = h; l4[j] = f2bf(v - bf2f(h));
        }
        *reinterpret_cast<u16x4*>(th + (size_t)(n0 + n) * K + k0 + c4) = h4;
        *reinterpret_cast<u16x4*>(tl + (size_t)(n0 + n) * K + k0 + c4) = l4;
    }
}

__global__ __launch_bounds__(256) void wconv_all(const float* __restrict__ Wq, const float* __restrict__ Wkv,
                                                 const float* __restrict__ Wo, const float* __restrict__ W1,
                                                 const float* __restrict__ W2,
                                                 u16* __restrict__ wqkvh, u16* __restrict__ wqkvl,
                                                 u16* __restrict__ woh, u16* __restrict__ wol,
                                                 u16* __restrict__ w1h, u16* __restrict__ w1l,
                                                 u16* __restrict__ w2h, u16* __restrict__ w2l) {
    int f = blockIdx.x;
    if (f < 16)       wconv_body(Wq,  wqkvh,               wqkvl,               256, 256,  f & 3,  f >> 2);
    else if (f < 48)  { int g = f - 16;  wconv_body(Wkv, wqkvh + 65536,       wqkvl + 65536,       256, 512,  g & 7,  g >> 3); }
    else if (f < 64)  { int g = f - 48;  wconv_body(Wo,  woh,                 wol,                 256, 256,  g & 3,  g >> 2); }
    else if (f < 128) { int g = f - 64;  wconv_body(W1,  w1h,                 w1l,                 256, 1024, g & 15, g >> 4); }
    else              { int g = f - 128; wconv_body(W2,  w2h,                 w2l,                 1024, 256, g & 3,  g >> 2); }
}

// ---------------- MFMA GEMM (bf16x2): dbuf gl16 staging, counted-vmcnt no-drain schedule ----------
// XCD-aware bijective block swizzle (grids divisible by 8): each XCD gets a contiguous by-band,
// so A-panel re-reads hit its own L2. Pure block->tile permutation (bit-identical output).
template<int BM, int BNT, int BK>
__global__ __launch_bounds__(256) void gemm_t(const u16* __restrict__ Ath, const u16* __restrict__ Atl,
                                              const u16* __restrict__ Bth, const u16* __restrict__ Btl,
                                              const float* __restrict__ bias, const float* __restrict__ resid,
                                              float* __restrict__ Cf, u16* __restrict__ Ch, u16* __restrict__ Cl,
                                              int M, int N, int K, int fuse_gelu) {
    __shared__ u16 Ah[2][BM * BK], Al[2][BM * BK];
    __shared__ u16 Bh[2][BNT * BK], Bl[2][BNT * BK];
    constexpr int WAVES_N = (BM == 128 && BNT == 64) ? 1 : 2;
    constexpr int WAVES_M = 4 / WAVES_N;
    constexpr int MI = BM / (16 * WAVES_M);
    constexpr int NI = BNT / (16 * WAVES_N);
    constexpr int SEGS = (BM + BNT) * BK / 1024;   // 1KB segments per wave per K-step
    constexpr int ROWS_SEG = 512 / BK;             // rows per segment
    constexpr int ASEG = BM / ROWS_SEG;            // segments per A h (or l) region
    constexpr int BSEG = BNT / ROWS_SEG;
    int t = threadIdx.x;
    // XCD-aware swizzle of the flattened block id (nwg % 8 == 0 for all launches)
    int gx = gridDim.x;
    int nwg = gx * gridDim.y;
    int lin = blockIdx.y * gx + blockIdx.x;
    int swz = (lin & 7) * (nwg >> 3) + (lin >> 3);
    int bx = swz % gx, by = swz / gx;
    int m0 = by * BM, n0 = bx * BNT;
    int L = t & 63, w = t >> 6, fr = L & 15, quad = L >> 4;
    int wm = (WAVES_N == 1) ? w : (w & 1);
    int wn = (WAVES_N == 1) ? 0 : (w >> 1);

    // per-seg global source (pre-swizzled col) + buf0 LDS dest + buf1 element delta
    const u16* gsrc[SEGS];
    u16* ldst[SEGS];
    u32 dlt[SEGS];
    {
        int lr, lc;
        if constexpr (BK == 32) { lr = L >> 2; lc = (L & 3) * 8; }
        else                    { lr = L >> 3; lc = (L & 7) * 8; }
#pragma unroll
        for (int i = 0; i < SEGS; i++) {
            int s = w * SEGS + i;
            const u16* gb; u16* lb; int r; u32 d;
            if (s < ASEG)                 { gb = Ath + (size_t)m0 * K; lb = &Ah[0][0]; r = s * ROWS_SEG;                 d = BM * BK; }
            else if (s < 2 * ASEG)        { gb = Atl + (size_t)m0 * K; lb = &Al[0][0]; r = (s - ASEG) * ROWS_SEG;        d = BM * BK; }
            else if (s < 2 * ASEG + BSEG) { gb = Bth + (size_t)n0 * K; lb = &Bh[0][0]; r = (s - 2 * ASEG) * ROWS_SEG;    d = BNT * BK; }
            else                          { gb = Btl + (size_t)n0 * K; lb = &Bl[0][0]; r = (s - 2 * ASEG - BSEG) * ROWS_SEG; d = BNT * BK; }
            int row = r + lr;
            int scol;
            if constexpr (BK == 32) scol = lc ^ (((row >> 1) & 3) << 3);
            else                    scol = lc ^ ((row & 7) << 3);
            gsrc[i] = gb + (size_t)row * K + scol;
            ldst[i] = lb + r * BK;
            dlt[i] = d;
        }
    }

    f32x4 acc[MI][NI];
#pragma unroll
    for (int i = 0; i < MI; i++)
#pragma unroll
        for (int j = 0; j < NI; j++) acc[i][j] = (f32x4){0.0f, 0.0f, 0.0f, 0.0f};

    const int NT = K / BK;
    // prologue: stage tile 0 into buf0
#pragma unroll
    for (int i = 0; i < SEGS; i++) gl16(gsrc[i], ldst[i]);

    for (int tt = 0; tt < NT; tt++) {
        asm volatile("s_waitcnt lgkmcnt(0)" ::: "memory");
        __builtin_amdgcn_s_barrier();            // A: buf^1 readers (tt-1) all done
        if (tt + 1 < NT) {
            int k0n = (tt + 1) * BK;
            u32 sel = (u32)((tt + 1) & 1);
#pragma unroll
            for (int i = 0; i < SEGS; i++) gl16(gsrc[i] + k0n, ldst[i] + sel * dlt[i]);
            asm volatile("s_waitcnt vmcnt(%0)" :: "n"(SEGS) : "memory");   // own tile tt landed
        } else {
            asm volatile("s_waitcnt vmcnt(0)" ::: "memory");
        }
        __builtin_amdgcn_s_barrier();            // B: everyone's tile tt landed
        __builtin_amdgcn_sched_barrier(0);
        int cb = tt & 1;
        const u16* AhB = &Ah[cb][0]; const u16* AlB = &Al[cb][0];
        const u16* BhB = &Bh[cb][0]; const u16* BlB = &Bl[cb][0];
#pragma unroll
        for (int kk = 0; kk < BK / 32; kk++) {
            int kc = kk * 32 + quad * 8;
            s16x8 ah[MI], al[MI];
#pragma unroll
            for (int mi = 0; mi < MI; mi++) {
                int row = wm * (MI * 16) + mi * 16 + fr;
                ah[mi] = *reinterpret_cast<const s16x8*>(&AhB[swk<BK>(row, kc)]);
                al[mi] = *reinterpret_cast<const s16x8*>(&AlB[swk<BK>(row, kc)]);
            }
            __builtin_amdgcn_s_setprio(1);
#pragma unroll
            for (int ni = 0; ni < NI; ni++) {
                int rn = wn * (NI * 16) + ni * 16 + fr;
                s16x8 bhf = *reinterpret_cast<const s16x8*>(&BhB[swk<BK>(rn, kc)]);
                s16x8 blf = *reinterpret_cast<const s16x8*>(&BlB[swk<BK>(rn, kc)]);
#pragma unroll
                for (int mi = 0; mi < MI; mi++) {
                    acc[mi][ni] = __builtin_amdgcn_mfma_f32_16x16x32_bf16(ah[mi], bhf, acc[mi][ni], 0, 0, 0);
                    acc[mi][ni] = __builtin_amdgcn_mfma_f32_16x16x32_bf16(ah[mi], blf, acc[mi][ni], 0, 0, 0);
                    acc[mi][ni] = __builtin_amdgcn_mfma_f32_16x16x32_bf16(al[mi], bhf, acc[mi][ni], 0, 0, 0);
                }
            }
            __builtin_amdgcn_s_setprio(0);
        }
    }
#pragma unroll
    for (int mi = 0; mi < MI; mi++) {
#pragma unroll
        for (int ni = 0; ni < NI; ni++) {
#pragma unroll
            for (int r = 0; r < 4; r++) {
                int row = m0 + wm * (MI * 16) + mi * 16 + quad * 4 + r;
                int col = n0 + wn * (NI * 16) + ni * 16 + fr;
                float v = acc[mi][ni][r];
                if (bias) v += bias[col];
                if (fuse_gelu) v = 0.5f * v * (1.0f + erff(v * 0.70710678118654752f));
                if (resid) v += resid[(size_t)row * N + col];
                size_t o = (size_t)row * N + col;
                if (Cf) Cf[o] = v;
                if (Ch) { u16 hh = f2bf(v); Ch[o] = hh; Cl[o] = f2bf(v - bf2f(hh)); }
            }
        }
    }
}

// ---------------- Attention v14: QBLK=128 (2 q-subtiles/wave), swapped QK^T in-lane softmax -------
// Per-q-row math identical to attn13 (bit-identical); K/V staging + barriers amortized over 2x rows.
__global__ __launch_bounds__(256) void attn14(const u16* __restrict__ qkvh, const u16* __restrict__ qkvl,
                                              u16* __restrict__ aoh, u16* __restrict__ aol) {
    int bh = blockIdx.x, b = bh >> 3, h = bh & 7;
    int qt = blockIdx.y;   // 0..7, 128 Q-rows each
    int t = threadIdx.x, L = t & 63, w = t >> 6;
    int fr = L & 15, quad = L >> 4;
    __shared__ u16 KH[2][64 * 32], KL[2][64 * 32];    // 16KB dbuf, sw32 layout
    __shared__ u16 VTH[32 * 64], VTL[32 * 64];        // 8KB  V^T[d][kc], sw64 layout
    __shared__ u16 PH[4][16 * 64], PL[4][16 * 64];    // 16KB per-wave P tile (reused by both subtiles)
    const float scale = 0.17677669529663687f;  // 1/sqrt(32)
    const int ROWS = 768;

    // K staging via gl16: 8 segs (KH 4, KL 4), 2 per wave, precomputed addresses
    const u16* ksrc[2];
    u16* kdst[2];
    {
        int lr = L >> 2, lc = (L & 3) * 8;
#pragma unroll
        for (int i = 0; i < 2; i++) {
            int s = w * 2 + i;
            const u16* gb = (s < 4) ? qkvh : qkvl;
            u16* lb = (s < 4) ? &KH[0][0] : &KL[0][0];
            int r = (s & 3) * 16;
            int row = r + lr;
            int scol = lc ^ (((row >> 1) & 3) << 3);
            ksrc[i] = gb + ((size_t)(b * 1024) + row) * ROWS + 256 + h * 32 + scol;
            kdst[i] = lb + r * 32;
        }
    }

    // Q fragments for both subtiles: rows qt*128 + w*16 + fr and +64
    size_t qoff0 = (size_t)(b * 1024 + qt * 128 + w * 16 + fr) * ROWS + h * 32 + quad * 8;
    s16x8 aqh0 = *reinterpret_cast<const s16x8*>(qkvh + qoff0);
    s16x8 aql0 = *reinterpret_cast<const s16x8*>(qkvl + qoff0);
    s16x8 aqh1 = *reinterpret_cast<const s16x8*>(qkvh + qoff0 + (size_t)64 * ROWS);
    s16x8 aql1 = *reinterpret_cast<const s16x8*>(qkvl + qoff0 + (size_t)64 * ROWS);

    // V loads: thread -> kc pair 2vp,2vp+1, dims vd0..+3
    int vp = t >> 3, vd0 = (t & 7) * 4;
    const u16* vh_ptr = qkvh + (size_t)(b * 1024 + 2 * vp) * ROWS + 512 + h * 32 + vd0;
    const u16* vl_ptr = qkvl + (size_t)(b * 1024 + 2 * vp) * ROWS + 512 + h * 32 + vd0;
    u16x4 vh0, vh1, vl0, vl1;
#define LOADV(kt_) do { size_t o_ = (size_t)((kt_) * 64) * ROWS;                                  \
        vh0 = *reinterpret_cast<const u16x4*>(vh_ptr + o_);                                       \
        vh1 = *reinterpret_cast<const u16x4*>(vh_ptr + o_ + ROWS);                                \
        vl0 = *reinterpret_cast<const u16x4*>(vl_ptr + o_);                                       \
        vl1 = *reinterpret_cast<const u16x4*>(vl_ptr + o_ + ROWS); } while (0)

    gl16(ksrc[0], kdst[0]);    // K(0) -> buf0 (must precede V(0) loads: FIFO drain invariant)
    gl16(ksrc[1], kdst[1]);
    MEMFENCE_ORDER();
    LOADV(0);

    float m_0 = -1e30f, l_0 = 0.0f, m_1 = -1e30f, l_1 = 0.0f;
    f32x4 accA0, accA1, accB0, accB1;   // subtile0: accA*, subtile1: accB* (ns 0/1)
    accA0 = (f32x4){0.0f, 0.0f, 0.0f, 0.0f}; accA1 = accA0; accB0 = accA0; accB1 = accA0;

// softmax + P-write + rescale + PV for one subtile (bit-identical to attn13's sequence)
#define SM_PV(SV, M_I, L_I, ACC0, ACC1) do {                                                      \
        float p[16];                                                                              \
        float ml = -1e30f;                                                                        \
        _Pragma("unroll")                                                                         \
        for (int ni = 0; ni < 4; ni++)                                                            \
            _Pragma("unroll")                                                                     \
            for (int r = 0; r < 4; r++) { float v = SV[ni][r] * scale; p[ni * 4 + r] = v; ml = fmaxf(ml, v); } \
        ml = fmaxf(ml, __shfl_xor(ml, 16));                                                       \
        ml = fmaxf(ml, __shfl_xor(ml, 32));                                                       \
        float mnew = fmaxf(M_I, ml);                                                              \
        float alpha = __expf(M_I - mnew);                                                         \
        M_I = mnew;                                                                               \
        float rs = 0.0f;                                                                          \
        _Pragma("unroll")                                                                         \
        for (int i = 0; i < 16; i++) { float e = __expf(p[i] - mnew); p[i] = e; rs += e; }        \
        rs += __shfl_xor(rs, 16);                                                                 \
        rs += __shfl_xor(rs, 32);                                                                 \
        L_I = L_I * alpha + rs;                                                                   \
        _Pragma("unroll")                                                                         \
        for (int ni = 0; ni < 4; ni++) {                                                          \
            float p0 = p[ni * 4], p1 = p[ni * 4 + 1], p2 = p[ni * 4 + 2], p3 = p[ni * 4 + 3];     \
            u32 qh01 = cvtpk(p0, p1), qh23 = cvtpk(p2, p3);                                       \
            float e0 = p0 - u2f(qh01 << 16);                                                      \
            float e1 = p1 - u2f(qh01 & 0xffff0000u);                                              \
            float e2 = p2 - u2f(qh23 << 16);                                                      \
            float e3 = p3 - u2f(qh23 & 0xffff0000u);                                              \
            u32 ql01 = cvtpk(e0, e1), ql23 = cvtpk(e2, e3);                                       \
            int c0 = sw64(fr, ni * 16 + quad * 4);                                                \
            int c1 = sw64(fr, ni * 16 + quad * 4 + 2);                                            \
            *reinterpret_cast<u32*>(&PH[w][c0]) = qh01;                                           \
            *reinterpret_cast<u32*>(&PH[w][c1]) = qh23;                                           \
            *reinterpret_cast<u32*>(&PL[w][c0]) = ql01;                                           \
            *reinterpret_cast<u32*>(&PL[w][c1]) = ql23;                                           \
        }                                                                                         \
        float a4[4];                                                                              \
        _Pragma("unroll")                                                                         \
        for (int r = 0; r < 4; r++) a4[r] = __shfl(alpha, quad * 4 + r);                          \
        ACC0[0] *= a4[0]; ACC0[1] *= a4[1]; ACC0[2] *= a4[2]; ACC0[3] *= a4[3];                   \
        ACC1[0] *= a4[0]; ACC1[1] *= a4[1]; ACC1[2] *= a4[2]; ACC1[3] *= a4[3];                   \
        __builtin_amdgcn_s_setprio(1);                                                            \
        _Pragma("unroll")                                                                         \
        for (int ks = 0; ks < 2; ks++) {                                                          \
            s16x8 aph = *reinterpret_cast<s16x8*>(&PH[w][sw64(fr, ks * 32 + quad * 8)]);          \
            s16x8 apl = *reinterpret_cast<s16x8*>(&PL[w][sw64(fr, ks * 32 + quad * 8)]);          \
            s16x8 bvh0 = *reinterpret_cast<s16x8*>(&VTH[sw64(fr, ks * 32 + quad * 8)]);           \
            s16x8 bvl0 = *reinterpret_cast<s16x8*>(&VTL[sw64(fr, ks * 32 + quad * 8)]);           \
            ACC0 = __builtin_amdgcn_mfma_f32_16x16x32_bf16(aph, bvh0, ACC0, 0, 0, 0);             \
            ACC0 = __builtin_amdgcn_mfma_f32_16x16x32_bf16(aph, bvl0, ACC0, 0, 0, 0);             \
            ACC0 = __builtin_amdgcn_mfma_f32_16x16x32_bf16(apl, bvh0, ACC0, 0, 0, 0);             \
            s16x8 bvh1 = *reinterpret_cast<s16x8*>(&VTH[sw64(16 + fr, ks * 32 + quad * 8)]);      \
            s16x8 bvl1 = *reinterpret_cast<s16x8*>(&VTL[sw64(16 + fr, ks * 32 + quad * 8)]);      \
            ACC1 = __builtin_amdgcn_mfma_f32_16x16x32_bf16(aph, bvh1, ACC1, 0, 0, 0);             \
            ACC1 = __builtin_amdgcn_mfma_f32_16x16x32_bf16(aph, bvl1, ACC1, 0, 0, 0);             \
            ACC1 = __builtin_amdgcn_mfma_f32_16x16x32_bf16(apl, bvh1, ACC1, 0, 0, 0);             \
        }                                                                                         \
        __builtin_amdgcn_s_setprio(0);                                                            \
    } while (0)

#pragma unroll 2
    for (int kt = 0; kt < 16; kt++) {
        int cur = kt & 1;
        BARRIER_LGKM();                // A: K buf^1 + VT readers (kt-1) all done
        if (kt < 15) {                 // prefetch K(kt+1) -> buf^1 (survives both barriers)
            size_t koff = (size_t)((kt + 1) * 64) * ROWS;
            u32 sel = (u32)((kt + 1) & 1) * (64 * 32);
            gl16(ksrc[0] + koff, kdst[0] + sel);
            gl16(ksrc[1] + koff, kdst[1] + sel);
        }
        {   // VT write from prefetched V regs; the implicit V-wait also drains K(kt) (landed long ago)
#pragma unroll
            for (int i = 0; i < 4; i++) {
                int idx = sw64(vd0 + i, 2 * vp);
                *reinterpret_cast<u32*>(&VTH[idx]) = (u32)vh0[i] | ((u32)vh1[i] << 16);
                *reinterpret_cast<u32*>(&VTL[idx]) = (u32)vl0[i] | ((u32)vl1[i] << 16);
            }
        }
        BARRIER_LGKM();                // B: K(kt) + VT(kt) ready for all waves
        // S^T = K Q^T for both subtiles: K frags loaded once, 3 MFMA each
        f32x4 sv0[4], sv1[4];
        __builtin_amdgcn_s_setprio(1);
#pragma unroll
        for (int ni = 0; ni < 4; ni++) {
            s16x8 bkh = *reinterpret_cast<s16x8*>(&KH[cur][sw32(ni * 16 + fr, quad * 8)]);
            s16x8 bkl = *reinterpret_cast<s16x8*>(&KL[cur][sw32(ni * 16 + fr, quad * 8)]);
            f32x4 c0 = (f32x4){0.0f, 0.0f, 0.0f, 0.0f};
            c0 = __builtin_amdgcn_mfma_f32_16x16x32_bf16(bkh, aqh0, c0, 0, 0, 0);
            c0 = __builtin_amdgcn_mfma_f32_16x16x32_bf16(bkl, aqh0, c0, 0, 0, 0);
            c0 = __builtin_amdgcn_mfma_f32_16x16x32_bf16(bkh, aql0, c0, 0, 0, 0);
            sv0[ni] = c0;
            f32x4 c1 = (f32x4){0.0f, 0.0f, 0.0f, 0.0f};
            c1 = __builtin_amdgcn_mfma_f32_16x16x32_bf16(bkh, aqh1, c1, 0, 0, 0);
            c1 = __builtin_amdgcn_mfma_f32_16x16x32_bf16(bkl, aqh1, c1, 0, 0, 0);
            c1 = __builtin_amdgcn_mfma_f32_16x16x32_bf16(bkh, aql1, c1, 0, 0, 0);
            sv1[ni] = c1;
        }
        __builtin_amdgcn_s_setprio(0);
        if (kt < 15) LOADV(kt + 1);    // V(kt+1) regs; consumed at next iter's VT write
        SM_PV(sv0, m_0, l_0, accA0, accA1);   // subtile 0 (P tile reused; same-wave ordering)
        SM_PV(sv1, m_1, l_1, accB0, accB1);   // subtile 1
    }
#undef SM_PV
#undef LOADV
    // write O as bf16 h/l: subtile 0 rows qt*128+w*16+quad*4+r, subtile 1 rows +64
    float invl0 = 1.0f / l_0, invl1 = 1.0f / l_1;
#pragma unroll
    for (int r = 0; r < 4; r++) {
        float iv0 = __shfl(invl0, quad * 4 + r);
        float iv1 = __shfl(invl1, quad * 4 + r);
        size_t rb0 = ((size_t)(b * 1024 + qt * 128 + w * 16 + quad * 4 + r)) * DMODEL + h * 32;
        size_t rb1 = rb0 + (size_t)64 * DMODEL;
        float v0 = accA0[r] * iv0, v1 = accA1[r] * iv0;
        u16 h0 = f2bf(v0); aoh[rb0 + fr] = h0;      aol[rb0 + fr] = f2bf(v0 - bf2f(h0));
        u16 h1 = f2bf(v1); aoh[rb0 + 16 + fr] = h1; aol[rb0 + 16 + fr] = f2bf(v1 - bf2f(h1));
        float v2 = accB0[r] * iv1, v3 = accB1[r] * iv1;
        u16 h2 = f2bf(v2); aoh[rb1 + fr] = h2;      aol[rb1 + fr] = f2bf(v2 - bf2f(h2));
        u16 h3 = f2bf(v3); aoh[rb1 + 16 + fr] = h3; aol[rb1 + 16 + fr] = f2bf(v3 - bf2f(h3));
    }
}

// ---------------- K-means: fused dist+argmin, stage-once centers, 2 rows/thread ------------------
__global__ __launch_bounds__(64) void csq_k(const float* __restrict__ centers, float* __restrict__ csq) {
    int j = blockIdx.x, l = threadIdx.x;
    float4 c4 = *reinterpret_cast<const float4*>(centers + j * DMODEL + l * 4);
    float s = c4.x * c4.x + c4.y * c4.y + c4.z * c4.z + c4.w * c4.w;
    for (int off = 1; off < 64; off <<= 1) s += __shfl_xor(s, off);
    if (l == 0) csq[j] = s;
}

// 32 rows x 64 clusters per block, 2 rows/thread; grid 256 (1 block/CU). Each staged-center b128
// read feeds BOTH rows -> LDS issue per row halved. k-ascending fp32 dot order per (row,cluster)
// identical to prior versions -> bit-identical labels.
__global__ __launch_bounds__(256) void km_distmin(const float* __restrict__ A, const float* __restrict__ Cn,
                                                  const float* __restrict__ csq, int* __restrict__ labels) {
    __shared__ float Cs[256][68];
    int t = threadIdx.x, tx = t & 15, ty = t >> 4;
    int m0 = blockIdx.x * 32;
    {   // stage centers transposed: thread -> col j = t&63, k-chunk (t>>6)*64
        int j = t & 63, kc = (t >> 6) * 64;
#pragma unroll
        for (int i = 0; i < 16; i++) {
            float4 c4 = *reinterpret_cast<const float4*>(Cn + (size_t)j * DMODEL + kc + i * 4);
            Cs[kc + i * 4 + 0][j] = c4.x; Cs[kc + i * 4 + 1][j] = c4.y;
            Cs[kc + i * 4 + 2][j] = c4.z; Cs[kc + i * 4 + 3][j] = c4.w;
        }
    }
    __syncthreads();
    const float* ar0 = A + (size_t)(m0 + ty) * DMODEL;
    const float* ar1 = A + (size_t)(m0 + 16 + ty) * DMODEL;
    float acc0[4] = {}, acc1[4] = {};
    for (int kb = 0; kb < 64; kb++) {
        float4 a0 = *reinterpret_cast<const float4*>(ar0 + kb * 4);
        float4 a1 = *reinterpret_cast<const float4*>(ar1 + kb * 4);
        float4 b0 = *reinterpret_cast<float4*>(&Cs[kb * 4 + 0][tx * 4]);
        float4 b1 = *reinterpret_cast<float4*>(&Cs[kb * 4 + 1][tx * 4]);
        float4 b2 = *reinterpret_cast<float4*>(&Cs[kb * 4 + 2][tx * 4]);
        float4 b3 = *reinterpret_cast<float4*>(&Cs[kb * 4 + 3][tx * 4]);
        acc0[0] += a0.x * b0.x; acc0[1] += a0.x * b0.y; acc0[2] += a0.x * b0.z; acc0[3] += a0.x * b0.w;
        acc0[0] += a0.y * b1.x; acc0[1] += a0.y * b1.y; acc0[2] += a0.y * b1.z; acc0[3] += a0.y * b1.w;
        acc0[0] += a0.z * b2.x; acc0[1] += a0.z * b2.y; acc0[2] += a0.z * b2.z; acc0[3] += a0.z * b2.w;
        acc0[0] += a0.w * b3.x; acc0[1] += a0.w * b3.y; acc0[2] += a0.w * b3.z; acc0[3] += a0.w * b3.w;
        acc1[0] += a1.x * b0.x; acc1[1] += a1.x * b0.y; acc1[2] += a1.x * b0.z; acc1[3] += a1.x * b0.w;
        acc1[0] += a1.y * b1.x; acc1[1] += a1.y * b1.y; acc1[2] += a1.y * b1.z; acc1[3] += a1.y * b1.w;
        acc1[0] += a1.z * b2.x; acc1[1] += a1.z * b2.y; acc1[2] += a1.z * b2.z; acc1[3] += a1.z * b2.w;
        acc1[0] += a1.w * b3.x; acc1[1] += a1.w * b3.y; acc1[2] += a1.w * b3.z; acc1[3] += a1.w * b3.w;
    }
    float4 cs4 = *reinterpret_cast<const float4*>(csq + tx * 4);
    float csv[4] = {cs4.x, cs4.y, cs4.z, cs4.w};
    {
        float best = csv[0] - 2.0f * acc0[0]; int bi = tx * 4;
#pragma unroll
        for (int j = 1; j < 4; j++) {
            float v = csv[j] - 2.0f * acc0[j];
            if (v < best) { best = v; bi = tx * 4 + j; }
        }
        for (int off = 1; off < 16; off <<= 1) {
            float ov = __shfl_xor(best, off);
            int oi = __shfl_xor(bi, off);
            if (ov < best || (ov == best && oi < bi)) { best = ov; bi = oi; }
        }
        if (tx == 0) labels[m0 + ty] = bi;
    }
    {
        float best = csv[0] - 2.0f * acc1[0]; int bi = tx * 4;
#pragma unroll
        for (int j = 1; j < 4; j++) {
            float v = csv[j] - 2.0f * acc1[j];
            if (v < best) { best = v; bi = tx * 4 + j; }
        }
        for (int off = 1; off < 16; off <<= 1) {
            float ov = __shfl_xor(best, off);
            int oi = __shfl_xor(bi, off);
            if (ov < best || (ov == best && oi < bi)) { best = ov; bi = oi; }
        }
        if (tx == 0) labels[m0 + 16 + ty] = bi;
    }
}

// block (c, j): scan chunk c's 256 labels, accumulate rows with lab==j. Uniform branch, no atomics.
__global__ __launch_bounds__(256) void km_segsum(const int* __restrict__ labels, const float* __restrict__ xf,
                                                 float* __restrict__ sums32, float* __restrict__ counts32) {
    int c = blockIdx.x, j = blockIdx.y, t = threadIdx.x;
    __shared__ int labs[256];
    if (t < 64) {
        int4 l4 = *reinterpret_cast<const int4*>(labels + c * 256 + t * 4);
        labs[t * 4] = l4.x; labs[t * 4 + 1] = l4.y; labs[t * 4 + 2] = l4.z; labs[t * 4 + 3] = l4.w;
    }
    __syncthreads();
    float acc = 0.0f, cnt = 0.0f;
    const float* xb = xf + (size_t)c * 256 * DMODEL;
    for (int i = 0; i < 256; i++) {
        if (labs[i] == j) { acc += xb[(size_t)i * DMODEL + t]; cnt += 1.0f; }
    }
    sums32[((size_t)c * NCLUST + j) * DMODEL + t] = acc;
    if (t == 0) counts32[c * NCLUST + j] = cnt;
}

__global__ __launch_bounds__(256) void km_update(float* __restrict__ centers, const float* __restrict__ sums32,
                                                 const float* __restrict__ counts32, float* __restrict__ csq) {
    __shared__ float red[256];
    int j = blockIdx.x, d = threadIdx.x;
    float c = 0.0f;
#pragma unroll
    for (int cc = 0; cc < 32; cc++) c += counts32[cc * NCLUST + j];
    float sv = 0.0f;
#pragma unroll
    for (int cc = 0; cc < 32; cc++) sv += sums32[((size_t)cc * NCLUST + j) * DMODEL + d];
    float cv = centers[j * DMODEL + d];
    if (c > 0.0f) cv = sv / fmaxf(c, 1.0f);
    centers[j * DMODEL + d] = cv;
    red[d] = cv * cv;
    __syncthreads();
    for (int off = 128; off; off >>= 1) { if (d < off) red[d] += red[d + off]; __syncthreads(); }
    if (d == 0) csq[j] = red[0];
}

__global__ __launch_bounds__(256) void nproj(const float* __restrict__ centers, const float* __restrict__ kW,
                                             const float* __restrict__ kb2, float* __restrict__ outc) {
    int idx = blockIdx.x * 256 + threadIdx.x;
    if (idx >= NCLUST * DMODEL) return;
    int row = idx >> 8, col = idx & 255;
    const float* cr = centers + row * DMODEL;
    float acc = 0.0f;
    for (int d = 0; d < DMODEL; d++) acc += cr[d] * kW[(size_t)d * DMODEL + col];
    outc[idx] = acc + kb2[col];
}

__global__ __launch_bounds__(256) void km_gather(const int* __restrict__ labels, const float* __restrict__ outc,
                                                 float* __restrict__ out) {
    int t = threadIdx.x;
#pragma unroll
    for (int r = 0; r < 4; r++) {
        int i = blockIdx.x * 4 + r;
        int lab = labels[i];
        out[(size_t)i * DMODEL + t] = outc[lab * DMODEL + t];
    }
}

extern "C" void kernel_launch(void* const* d_in, const int* in_sizes, int n_in,
                              void* d_out, int out_size, void* d_ws, size_t ws_size,
                              hipStream_t stream) {
    const float* x_in  = (const float*)d_in[0];
    const float* ln1_g = (const float*)d_in[1];
    const float* ln1_b = (const float*)d_in[2];
    const float* Wq    = (const float*)d_in[3];
    const float* Wkv   = (const float*)d_in[4];
    const float* Wo    = (const float*)d_in[5];
    const float* bo    = (const float*)d_in[6];
    const float* ln2_g = (const float*)d_in[7];
    const float* ln2_b = (const float*)d_in[8];
    const float* W1    = (const float*)d_in[9];
    const float* b1    = (const float*)d_in[10];
    const float* W2    = (const float*)d_in[11];
    const float* b2    = (const float*)d_in[12];
    const float* kWp   = (const float*)d_in[13];
    const float* kbp   = (const float*)d_in[14];
    float* out = (float*)d_out;

    const size_t NEEDED = 53477376;
    if (ws_size < NEEDED) {
        hipMemsetAsync(d_out, 0, (size_t)out_size * sizeof(float), stream);
        return;   // signature: absmax ~0.707 => workspace too small
    }

    char* ws = (char*)d_ws;
    float* xf      = (float*)(ws);                 // 8 MB fp32 residual stream
    u16*   xnh     = (u16*)  (ws + 8388608);       // 4 MB  ln out h
    u16*   xnl     = (u16*)  (ws + 12582912);      // 4 MB  ln out l
    u16*   aoh     = xnh;                          // attn out aliases xn (xn dead after QKV gemm)
    u16*   aol     = xnl;
    u16*   qkvh    = (u16*)  (ws + 16777216);      // 12 MB (8192x768 u16) -> ends 29360128
    u16*   qkvl    = (u16*)  (ws + 29360128);      // 12 MB -> ends 41943040
    u16*   hbh     = (u16*)  (ws + 16777216);      // 16 MB (qkv dead during FFN)
    u16*   hbl     = (u16*)  (ws + 33554432);      // 16 MB -> ends 50331648
    float* centers = (float*)(ws + 41943040);      // 64 KB -> 42008576
    float* csqb    = (float*)(ws + 42008576);      // 256 B -> 42008832
    float* counts32= (float*)(ws + 42008832);      // 8 KB  -> 42017024
    int*   labels  = (int*)  (ws + 42017024);      // 32 KB -> 42049792
    float* outc    = (float*)(ws + 42049792);      // 64 KB -> 42115328
    float* sums32  = (float*)(ws + 42115328);      // 2 MB  -> 44212480
    u16*   wr      = (u16*)  (ws + 50331648);
    u16 *wqkvh = wr,          *wqkvl = wr + 196608;   // 768x256 each
    u16 *woh = wr + 393216,   *wol = wr + 458752;
    u16 *w1h = wr + 524288,   *w1l = wr + 786432;
    u16 *w2h = wr + 1048576,  *w2l = wr + 1310720;

    hipMemcpyAsync(xf, x_in, (size_t)BN * DMODEL * sizeof(float), hipMemcpyDeviceToDevice, stream);

    for (int l = 0; l < 4; l++) {
        wconv_all<<<192, 256, 0, stream>>>(Wq + (size_t)l * 65536, Wkv + (size_t)l * 131072,
                                           Wo + (size_t)l * 65536, W1 + (size_t)l * 262144,
                                           W2 + (size_t)l * 262144,
                                           wqkvh, wqkvl, woh, wol, w1h, w1l, w2h, w2l);

        ln_wave<<<BN / 4, 256, 0, stream>>>(xf, ln1_g + l * 256, ln1_b + l * 256, xnh, xnl);
        gemm_t<128, 128, 32><<<dim3(6, 64), 256, 0, stream>>>(xnh, xnl, wqkvh, wqkvl, nullptr, nullptr,
                                                              nullptr, qkvh, qkvl, BN, 768, 256, 0);
        attn14<<<dim3(64, 8), 256, 0, stream>>>(qkvh, qkvl, aoh, aol);
        gemm_t<64, 64, 64><<<dim3(4, 128), 256, 0, stream>>>(aoh, aol, woh, wol, bo + l * 256, xf,
                                                             xf, nullptr, nullptr, BN, 256, 256, 0);
        ln_wave<<<BN / 4, 256, 0, stream>>>(xf, ln2_g + l * 256, ln2_b + l * 256, xnh, xnl);
        gemm_t<128, 128, 32><<<dim3(8, 64), 256, 0, stream>>>(xnh, xnl, w1h, w1l, b1 + l * 1024, nullptr,
                                                              nullptr, hbh, hbl, BN, 1024, 256, 1);
        gemm_t<64, 64, 64><<<dim3(4, 128), 256, 0, stream>>>(hbh, hbl, w2h, w2l, b2 + l * 256, xf,
                                                             xf, nullptr, nullptr, BN, 256, 1024, 0);
    }

    hipMemcpyAsync(centers, xf, NCLUST * DMODEL * sizeof(float), hipMemcpyDeviceToDevice, stream);
    csq_k<<<64, 64, 0, stream>>>(centers, csqb);
    for (int it = 0; it < 10; it++) {
        km_distmin<<<256, 256, 0, stream>>>(xf, centers, csqb, labels);
        km_segsum<<<dim3(32, NCLUST), 256, 0, stream>>>(labels, xf, sums32, counts32);
        km_update<<<64, 256, 0, stream>>>(centers, sums32, counts32, csqb);
    }
    km_distmin<<<256, 256, 0, stream>>>(xf, centers, csqb, labels);
    nproj<<<64, 256, 0, stream>>>(centers, kWp, kbp, outc);
    km_gather<<<BN / 4, 256, 0, stream>>>(labels, outc, out);
}